// Round 15
// baseline (2159.439 us; speedup 1.0000x reference)
//
#include <hip/hip_runtime.h>
#include <stdint.h>

typedef __attribute__((ext_vector_type(8))) short short8;
typedef __attribute__((ext_vector_type(4))) float f32x4;
typedef __attribute__((ext_vector_type(4))) unsigned int u32x4;

#define B_    32
#define T_    512
#define E_    300
#define KE_   384     // padded embed K (4-wave x 96 split)
#define H_    1024
#define G4_   4096
#define R_    30
#define AD_   350
#define AC_   384
#define MH_   512
#define FEAT_ 61440
#define NU_   16      // hidden units per (dir,w) group
#define DTICK 16ull   // pacing delta: ~0.64us @ 25MHz RTC

__device__ __forceinline__ unsigned short f2bu(float f) {
  unsigned int x = __builtin_bit_cast(unsigned int, f);
  x += 0x7fffu + ((x >> 16) & 1u);
  return (unsigned short)(x >> 16);
}
__device__ __forceinline__ float b2f(unsigned short u) {
  return __builtin_bit_cast(float, (unsigned int)u << 16);
}
__device__ __forceinline__ float sigm(float x) {
  return __builtin_amdgcn_rcpf(1.f + __expf(-x));
}
__device__ __forceinline__ float tanh_fast(float x) {
  return 1.f - 2.f * __builtin_amdgcn_rcpf(1.f + __expf(2.f * x));
}

// 8x dwordx4 gather issue (no waitcnt): 2 bases x 4 imm offsets (ktl steps)
#define BULK8G_ISS(b0p, b1p, FL)                                                \
  asm volatile(                                                                 \
      "global_load_dwordx4 %0, %8, off " FL "\n\t"                              \
      "global_load_dwordx4 %1, %8, off offset:1024 " FL "\n\t"                  \
      "global_load_dwordx4 %2, %8, off offset:2048 " FL "\n\t"                  \
      "global_load_dwordx4 %3, %8, off offset:3072 " FL "\n\t"                  \
      "global_load_dwordx4 %4, %9, off " FL "\n\t"                              \
      "global_load_dwordx4 %5, %9, off offset:1024 " FL "\n\t"                  \
      "global_load_dwordx4 %6, %9, off offset:2048 " FL "\n\t"                  \
      "global_load_dwordx4 %7, %9, off offset:3072 " FL                         \
      : "=&v"(q0), "=&v"(q1), "=&v"(q2), "=&v"(q3),                             \
        "=&v"(q4), "=&v"(q5), "=&v"(q6), "=&v"(q7)                              \
      : "v"(b0p), "v"(b1p)                                                      \
      : "memory")

#define BULK8G(b0p, b1p, FL)                                                    \
  do {                                                                          \
    BULK8G_ISS(b0p, b1p, FL);                                                   \
    asm volatile("s_waitcnt vmcnt(0)" ::: "memory");                            \
    __builtin_amdgcn_sched_barrier(0);                                          \
  } while (0)

// validate: any bf16 half with bit14 set => sentinel/unwritten
#define VAL8(BAD)                                                               \
  {                                                                             \
    u32x4 o01 = q0 | q1, o23 = q2 | q3, o45 = q4 | q5, o67 = q6 | q7;           \
    u32x4 ov4 = (o01 | o23) | (o45 | o67);                                      \
    unsigned ovv = (ov4[0] | ov4[1]) | (ov4[2] | ov4[3]);                       \
    BAD = (ovv & 0x40004000u) != 0;                                             \
  }

// ---------------------------------------------------------------------------
// K0: cast/pad to bf16: xb[16384][384], wihb[8192][384], w1b[384][2048],
//     wmlpb[512][61440]
// ---------------------------------------------------------------------------
__global__ void k0_prep(const int* __restrict__ inp, const float* __restrict__ W_emb,
                        const float* __restrict__ W_ih, const float* __restrict__ W1,
                        const float* __restrict__ W_mlp,
                        unsigned short* __restrict__ xb, unsigned short* __restrict__ wihb,
                        unsigned short* __restrict__ w1b, unsigned short* __restrict__ wmlpb) {
  const int N1 = 16384 * KE_;
  const int N2 = 8192 * KE_;
  const int N3 = AC_ * 2048;
  const int N4 = MH_ * FEAT_;
  const int NT = N1 + N2 + N3 + N4;
  for (int i = blockIdx.x * blockDim.x + threadIdx.x; i < NT; i += gridDim.x * blockDim.x) {
    if (i < N1) {
      int row = i / KE_, e = i - row * KE_;
      float v = (e < E_) ? W_emb[(size_t)inp[row] * E_ + e] : 0.f;
      xb[i] = f2bu(v);
    } else if (i < N1 + N2) {
      int j = i - N1;
      int rw = j / KE_, e = j - rw * KE_;
      float v = (e < E_) ? W_ih[(size_t)rw * E_ + e] : 0.f;
      wihb[j] = f2bu(v);
    } else if (i < N1 + N2 + N3) {
      int j = i - N1 - N2;
      int a = j >> 11, k = j & 2047;
      float v = (a < AD_) ? W1[(size_t)a * 2048 + k] : 0.f;
      w1b[j] = f2bu(v);
    } else {
      int j = i - N1 - N2 - N3;
      wmlpb[j] = f2bu(W_mlp[j]);
    }
  }
}

// ---------------------------------------------------------------------------
// K2 v15: v14 batch-split swarm with the step pipeline reordered:
//   pace FIRST (absorbs loop overhead) -> issue gather -> xbf loads +
//   x-GEMM (gather RT and xbf RT overlap; single merged vmcnt wait) ->
//   validate -> h-MFMA.  Removes the serial xbfRT + pace + gatherRT chain.
// ---------------------------------------------------------------------------
__global__ __launch_bounds__(256, 1) void k2_rnn(const float* __restrict__ Whh,
                                                 const unsigned short* __restrict__ wihb,
                                                 const unsigned short* __restrict__ xb,
                                                 const float* __restrict__ b_ih,
                                                 const float* __restrict__ b_hh,
                                                 unsigned short* __restrict__ outb,
                                                 unsigned short* __restrict__ hpub) {
  const int dir = blockIdx.x >> 7;
  const int w = (blockIdx.x >> 1) & 63;
  const int bh = blockIdx.x & 1;
  const int tid = threadIdx.x;
  const int wid = tid >> 6, lane = tid & 63;
  const int l15 = lane & 15, lg = lane >> 4;

  __shared__ float Gp[4][4][16][17];               // [wave][gate][batch16][unit+pad]
  __shared__ __align__(16) unsigned short htmp[16][16];

  // ---- preload W_hh K-quarter as bf16 A-frags (units 0..15, 4 gates) ---
  short8 afr[4][8];
  {
    const int kq = wid << 8;
#pragma unroll
    for (int g = 0; g < 4; ++g) {
      const float* wp = Whh + ((size_t)dir * G4_ + g * H_ + w * NU_ + l15) * H_ + kq + lg * 8;
#pragma unroll
      for (int ktl = 0; ktl < 8; ++ktl) {
        float4 f0 = *(const float4*)(wp + ktl * 32);
        float4 f1 = *(const float4*)(wp + ktl * 32 + 4);
        short8 s;
        s[0] = (short)f2bu(f0.x); s[1] = (short)f2bu(f0.y);
        s[2] = (short)f2bu(f0.z); s[3] = (short)f2bu(f0.w);
        s[4] = (short)f2bu(f1.x); s[5] = (short)f2bu(f1.y);
        s[6] = (short)f2bu(f1.z); s[7] = (short)f2bu(f1.w);
        afr[g][ktl] = s;
      }
    }
  }

  // ---- preload W_ih K-slice (96 of 384) as bf16 A-frags ----------------
  const int kqx = wid * 96;
  short8 axr[4][3];
#pragma unroll
  for (int g = 0; g < 4; ++g) {
    const unsigned short* xp = wihb + ((size_t)dir * G4_ + g * H_ + w * NU_ + l15) * KE_ + kqx + lg * 8;
#pragma unroll
    for (int kt = 0; kt < 3; ++kt) axr[g][kt] = *(const short8*)(xp + kt * 32);
  }

  const int u = tid >> 4;    // activation role: unit 0..15
  const int b = tid & 15;    // activation role: batch-within-half 0..15

  float bsum[4];
#pragma unroll
  for (int g = 0; g < 4; ++g) {
    int row = dir * G4_ + g * H_ + w * NU_ + u;
    bsum[g] = b_ih[row] + b_hh[row];
  }

  // gather/poll offsets within a (dir,t,bh) slot of 64 chunks x 256 ushorts
  const size_t hlane = (size_t)(wid * 16 + (lg >> 1)) * 256 + l15 * 16 + (lg & 1) * 8;
  const size_t hpoll = (size_t)(wid * 16 + (lane & 15)) * 256;

  float cst = 0.f;
  unsigned long long pprev = __builtin_amdgcn_s_memrealtime();

#pragma unroll 1
  for (int s = 0; s < T_; ++s) {
    const int t = dir ? (T_ - 1 - s) : s;

    f32x4 acc[4];
#pragma unroll
    for (int g = 0; g < 4; ++g) acc[g] = (f32x4){0.f, 0.f, 0.f, 0.f};

    u32x4 q0, q1, q2, q3, q4, q5, q6, q7;
    const unsigned short* hbase = hpub;   // dummy init
    const int have_h = (s > 0);

    if (have_h) {
      const int tsrc = dir ? t + 1 : t - 1;
      hbase = hpub + ((size_t)(dir * T_ + tsrc) * 2 + bh) * 16384;

      // -- pace FIRST: spin on scalar clock until own prev publish + DTICK
      {
        unsigned long long tgt = pprev + DTICK;
        unsigned long long now;
        do { now = __builtin_amdgcn_s_memrealtime(); } while (now < tgt);
      }

      // -- issue speculative gather (sc0); do NOT wait yet ---------------
      const unsigned short* B0 = hbase + hlane;
      const unsigned short* B1 = B0 + 4096;
      BULK8G_ISS(B0, B1, "sc0");
    }
    __builtin_amdgcn_sched_barrier(0);

    // -- xbf loads + x-GEMM: RT overlaps the gather RT (merged wait) -----
    {
      short8 xbf[3];
#pragma unroll
      for (int kt = 0; kt < 3; ++kt)
        xbf[kt] = *(const short8*)(xb + ((size_t)(bh * 16 + l15) * T_ + t) * KE_ + kqx + kt * 32 + lg * 8);
#pragma unroll
      for (int kt = 0; kt < 3; ++kt)
#pragma unroll
        for (int g = 0; g < 4; ++g)
          acc[g] = __builtin_amdgcn_mfma_f32_16x16x32_bf16(axr[g][kt], xbf[kt], acc[g], 0, 0, 0);
    }
    __builtin_amdgcn_sched_barrier(0);

    if (have_h) {
      asm volatile("s_waitcnt vmcnt(0)" ::: "memory");
      __builtin_amdgcn_sched_barrier(0);
      bool bad; VAL8(bad);
      if (__builtin_expect(bad, 0)) {
        // backstop: thin-poll this wave's 16 producer chunks, then retry
        const unsigned short* sp = hbase + hpoll;
        unsigned v;
        int guard = 0;
        for (;;) {
          asm volatile("global_load_dword %0, %1, off sc0 sc1\n\ts_waitcnt vmcnt(0)"
                       : "=v"(v) : "v"(sp) : "memory");
          if (__all(!(v & 0x40004000u))) break;
          if (++guard > 50000) break;   // hang safety; never trips co-resident
        }
        const unsigned short* B0 = hbase + hlane;
        const unsigned short* B1 = B0 + 4096;
        int g2 = 0;
        do {
          BULK8G(B0, B1, "sc0 sc1");
          VAL8(bad);
        } while (bad && ++g2 < 50000);
      }

      short8 bf[8];
      bf[0] = __builtin_bit_cast(short8, q0); bf[1] = __builtin_bit_cast(short8, q1);
      bf[2] = __builtin_bit_cast(short8, q2); bf[3] = __builtin_bit_cast(short8, q3);
      bf[4] = __builtin_bit_cast(short8, q4); bf[5] = __builtin_bit_cast(short8, q5);
      bf[6] = __builtin_bit_cast(short8, q6); bf[7] = __builtin_bit_cast(short8, q7);

#pragma unroll
      for (int ktl = 0; ktl < 8; ++ktl)
#pragma unroll
        for (int g = 0; g < 4; ++g)
          acc[g] = __builtin_amdgcn_mfma_f32_16x16x32_bf16(afr[g][ktl], bf[ktl], acc[g], 0, 0, 0);
    }

    // -- write K-partial sums to LDS -------------------------------------
#pragma unroll
    for (int g = 0; g < 4; ++g)
#pragma unroll
      for (int j = 0; j < 4; ++j)
        Gp[wid][g][l15][lg * 4 + j] = acc[g][j];
    __syncthreads();

    // -- activations: thread handles (u, b) ------------------------------
    {
      float gi = Gp[0][0][b][u] + Gp[1][0][b][u] + Gp[2][0][b][u] + Gp[3][0][b][u] + bsum[0];
      float gf = Gp[0][1][b][u] + Gp[1][1][b][u] + Gp[2][1][b][u] + Gp[3][1][b][u] + bsum[1];
      float gg = Gp[0][2][b][u] + Gp[1][2][b][u] + Gp[2][2][b][u] + Gp[3][2][b][u] + bsum[2];
      float go = Gp[0][3][b][u] + Gp[1][3][b][u] + Gp[2][3][b][u] + Gp[3][3][b][u] + bsum[3];
      cst = sigm(gf) * cst + sigm(gi) * tanh_fast(gg);
      float hv = sigm(go) * tanh_fast(cst);
      htmp[b][u] = f2bu(hv);
    }
    __syncthreads();

    // -- record anchor; wave 0 publishes chunk (512B contiguous) + outb --
    pprev = __builtin_amdgcn_s_memrealtime();
    if (tid < 64) {
      int bb = tid >> 2, q = tid & 3;
      uint2 v = *(const uint2*)&htmp[bb][q * 4];
      unsigned short* hp = hpub + ((size_t)(dir * T_ + t) * 2 + bh) * 16384 + (size_t)w * 256 + bb * 16 + q * 4;
      asm volatile("global_store_dwordx2 %0, %1, off sc0 sc1" :: "v"(hp), "v"(v) : "memory");
      *(uint2*)(outb + ((size_t)(bh * 16 + bb) * T_ + t) * 2048 + dir * H_ + w * NU_ + q * 4) = v;
    }
  }
}

// ---------------------------------------------------------------------------
// K3: th1[row][a] = tanh( out[row][:] . W1b[a][:] )
// ---------------------------------------------------------------------------
__global__ __launch_bounds__(256, 1) void k3_s1(const unsigned short* __restrict__ outb,
                                                const unsigned short* __restrict__ w1b,
                                                unsigned short* __restrict__ th1) {
  const int rb = blockIdx.x;
  const int wid = threadIdx.x >> 6, lane = threadIdx.x & 63;
  const int m = wid & 1, nh = wid >> 1;
  const int l15 = lane & 15, lg = lane >> 4;

  f32x4 acc[12];
#pragma unroll
  for (int nt = 0; nt < 12; ++nt) acc[nt] = (f32x4){0.f, 0.f, 0.f, 0.f};

  const unsigned short* arow = outb + ((size_t)rb * 32 + m * 16 + l15) * 2048;
  for (int kt = 0; kt < 64; ++kt) {
    short8 af = *(const short8*)(arow + kt * 32 + lg * 8);
#pragma unroll
    for (int nt = 0; nt < 12; ++nt) {
      int col = nh * 192 + nt * 16 + l15;
      short8 bf = *(const short8*)(w1b + (size_t)col * 2048 + kt * 32 + lg * 8);
      acc[nt] = __builtin_amdgcn_mfma_f32_16x16x32_bf16(af, bf, acc[nt], 0, 0, 0);
    }
  }
#pragma unroll
  for (int nt = 0; nt < 12; ++nt) {
#pragma unroll
    for (int j = 0; j < 4; ++j) {
      int row = rb * 32 + m * 16 + lg * 4 + j;
      int col = nh * 192 + nt * 16 + l15;
      th1[(size_t)row * AC_ + col] = f2bu(tanh_fast(acc[nt][j]));
    }
  }
}

// ---------------------------------------------------------------------------
// K4: abuf[b][r][t] = th1[row][:350] . W2[r][:350]
// ---------------------------------------------------------------------------
__global__ void k4_s2(const unsigned short* __restrict__ th1, const float* __restrict__ W2,
                      float* __restrict__ abuf) {
  int idx = blockIdx.x * 256 + threadIdx.x;
  int row = idx >> 5, r = idx & 31;
  if (r >= R_) return;
  const unsigned short* tp = th1 + (size_t)row * AC_;
  const float* wp = W2 + r * AD_;
  float acc = 0.f;
  for (int a = 0; a < AD_; ++a) acc = fmaf(b2f(tp[a]), wp[a], acc);
  int b = row >> 9, t = row & 511;
  abuf[((size_t)b * R_ + r) * T_ + t] = acc;
}

// ---------------------------------------------------------------------------
// K5: masked softmax over t (in place).  One wave per (b,r).
// ---------------------------------------------------------------------------
__global__ void k5_sm(float* __restrict__ abuf, const int* __restrict__ lens) {
  int wv = blockIdx.x * 4 + (threadIdx.x >> 6);
  int lane = threadIdx.x & 63;
  if (wv >= B_ * R_) return;
  int b = wv / R_, r = wv % R_;
  int len = lens[b];
  float* row = abuf + ((size_t)b * R_ + r) * T_;
  float v[8];
  float mx = -1e30f;
#pragma unroll
  for (int i = 0; i < 8; ++i) {
    int t = lane + i * 64;
    float x = (t < len) ? row[t] : -1e30f;
    v[i] = x;
    mx = fmaxf(mx, x);
  }
#pragma unroll
  for (int o = 32; o > 0; o >>= 1) mx = fmaxf(mx, __shfl_xor(mx, o));
  float sum = 0.f;
#pragma unroll
  for (int i = 0; i < 8; ++i) {
    float e = (v[i] > -1e29f) ? __expf(v[i] - mx) : 0.f;
    v[i] = e;
    sum += e;
  }
#pragma unroll
  for (int o = 32; o > 0; o >>= 1) sum += __shfl_xor(sum, o);
  float inv = 1.f / sum;
#pragma unroll
  for (int i = 0; i < 8; ++i) row[lane + i * 64] = v[i] * inv;
}

// ---------------------------------------------------------------------------
// K6: M[b][r][h] = sum_t A[b][r][t] * out[b][t][h].  Writes mbuf as bf16.
// ---------------------------------------------------------------------------
__global__ __launch_bounds__(256) void k6_m(const float* __restrict__ abuf,
                                            const unsigned short* __restrict__ outb,
                                            unsigned short* __restrict__ mbuf) {
  int b = blockIdx.x >> 4, hb = blockIdx.x & 15;
  __shared__ float As[R_ * T_];
  for (int i = threadIdx.x; i < R_ * T_; i += 256) As[i] = abuf[(size_t)b * R_ * T_ + i];
  __syncthreads();
  int h = threadIdx.x & 127, rh = threadIdx.x >> 7;
  float acc[15];
#pragma unroll
  for (int rr = 0; rr < 15; ++rr) acc[rr] = 0.f;
  const unsigned short* op = outb + (size_t)b * T_ * 2048 + hb * 128 + h;
  for (int t = 0; t < T_; ++t) {
    float vv = b2f(op[(size_t)t * 2048]);
#pragma unroll
    for (int rr = 0; rr < 15; ++rr) acc[rr] = fmaf(As[(rh * 15 + rr) * T_ + t], vv, acc[rr]);
  }
#pragma unroll
  for (int rr = 0; rr < 15; ++rr)
    mbuf[(size_t)b * FEAT_ + (size_t)(rh * 15 + rr) * 2048 + hb * 128 + h] = f2bu(acc[rr]);
}

// ---------------------------------------------------------------------------
// K7: per-sample penalty partial: ||A A^T - I||_F^2.
// ---------------------------------------------------------------------------
__global__ __launch_bounds__(256) void k7_pen(const float* __restrict__ abuf,
                                              float* __restrict__ penp) {
  int b = blockIdx.x;
  __shared__ float As[R_ * 515];
  __shared__ float red[256];
  for (int i = threadIdx.x; i < R_ * T_; i += 256) {
    int r = i >> 9, t = i & 511;
    As[r * 515 + t] = abuf[(size_t)b * R_ * T_ + i];
  }
  __syncthreads();
  float psum = 0.f;
  for (int p = threadIdx.x; p < R_ * R_; p += 256) {
    int r = p / R_, s = p % R_;
    const float* pr = As + r * 515;
    const float* ps = As + s * 515;
    float d = 0.f;
    for (int t = 0; t < T_; ++t) d = fmaf(pr[t], ps[t], d);
    d -= (r == s) ? 1.f : 0.f;
    psum += d * d;
  }
  red[threadIdx.x] = psum;
  __syncthreads();
  for (int o = 128; o > 0; o >>= 1) {
    if (threadIdx.x < o) red[threadIdx.x] += red[threadIdx.x + o];
    __syncthreads();
  }
  if (threadIdx.x == 0) penp[b] = red[0];
}

// ---------------------------------------------------------------------------
// K8 v2: hidsum[b][m] += wmlpb[m-tile][k-tile] . mbuf[b][k-tile]  (MFMA)
// ---------------------------------------------------------------------------
__global__ __launch_bounds__(256, 1) void k8_mlp(const unsigned short* __restrict__ wmlpb,
                                                 const unsigned short* __restrict__ mbuf,
                                                 float* __restrict__ hid) {
  const int mblk = blockIdx.x >> 4, kblk = blockIdx.x & 15;
  const int wid = threadIdx.x >> 6, lane = threadIdx.x & 63;
  const int l15 = lane & 15, lg = lane >> 4;
  const int kq = kblk * 3840 + wid * 960;

  f32x4 acc[2][2];
#pragma unroll
  for (int i = 0; i < 2; ++i)
#pragma unroll
    for (int j = 0; j < 2; ++j) acc[i][j] = (f32x4){0.f, 0.f, 0.f, 0.f};

  const unsigned short* ap0 = wmlpb + (size_t)(mblk * 32 + l15) * FEAT_ + kq + lg * 8;
  const unsigned short* ap1 = ap0 + (size_t)16 * FEAT_;
  const unsigned short* bp0 = mbuf + (size_t)l15 * FEAT_ + kq + lg * 8;
  const unsigned short* bp1 = bp0 + (size_t)16 * FEAT_;
  for (int kt = 0; kt < 30; ++kt) {
    short8 a0 = *(const short8*)(ap0 + kt * 32);
    short8 a1 = *(const short8*)(ap1 + kt * 32);
    short8 b0 = *(const short8*)(bp0 + kt * 32);
    short8 b1 = *(const short8*)(bp1 + kt * 32);
    acc[0][0] = __builtin_amdgcn_mfma_f32_16x16x32_bf16(a0, b0, acc[0][0], 0, 0, 0);
    acc[0][1] = __builtin_amdgcn_mfma_f32_16x16x32_bf16(a0, b1, acc[0][1], 0, 0, 0);
    acc[1][0] = __builtin_amdgcn_mfma_f32_16x16x32_bf16(a1, b0, acc[1][0], 0, 0, 0);
    acc[1][1] = __builtin_amdgcn_mfma_f32_16x16x32_bf16(a1, b1, acc[1][1], 0, 0, 0);
  }

  __shared__ float red[4][32][33];
#pragma unroll
  for (int mi = 0; mi < 2; ++mi)
#pragma unroll
    for (int ni = 0; ni < 2; ++ni)
#pragma unroll
      for (int j = 0; j < 4; ++j)
        red[wid][mi * 16 + lg * 4 + j][ni * 16 + l15] = acc[mi][ni][j];
  __syncthreads();

  int m = threadIdx.x >> 3, b4 = (threadIdx.x & 7) * 4;
#pragma unroll
  for (int k = 0; k < 4; ++k) {
    int bb = b4 + k;
    float s = red[0][m][bb] + red[1][m][bb] + red[2][m][bb] + red[3][m][bb];
    atomicAdd(&hid[(size_t)bb * MH_ + mblk * 32 + m], s);
  }
}

// ---------------------------------------------------------------------------
// K9: decoded = softmax( relu(hid+b_mlp) @ W_dec^T + b_dec ); penal = mean.
// ---------------------------------------------------------------------------
__global__ void k9_out(const float* __restrict__ hid, const float* __restrict__ b_mlp,
                       const float* __restrict__ W_dec, const float* __restrict__ b_dec,
                       const float* __restrict__ penp, float* __restrict__ out) {
  int tid = threadIdx.x;
  if (tid < 64) {
    int b = tid >> 1, c = tid & 1;
    const float* hp = hid + (size_t)b * MH_;
    const float* wp = W_dec + (size_t)c * MH_;
    float acc = b_dec[c];
    for (int k = 0; k < MH_; ++k) {
      float hk = fmaxf(hp[k] + b_mlp[k], 0.f);
      acc = fmaf(hk, wp[k], acc);
    }
    float other = __shfl_xor(acc, 1);
    float mx = fmaxf(acc, other);
    float e = __expf(acc - mx), eo = __expf(other - mx);
    out[b * 2 + c] = e / (e + eo);
  } else if (tid == 64) {
    float s = 0.f;
    for (int b = 0; b < B_; ++b) s += penp[b];
    out[64] = s * (1.f / 32.f);
  }
}

// ---------------------------------------------------------------------------
extern "C" void kernel_launch(void* const* d_in, const int* in_sizes, int n_in,
                              void* d_out, int out_size, void* d_ws, size_t ws_size,
                              hipStream_t stream) {
  const int* inp = (const int*)d_in[0];
  const int* lens = (const int*)d_in[1];
  const float* W_emb = (const float*)d_in[2];
  const float* W_ih = (const float*)d_in[3];
  const float* W_hh = (const float*)d_in[4];
  const float* b_ih = (const float*)d_in[5];
  const float* b_hh = (const float*)d_in[6];
  const float* W1 = (const float*)d_in[7];
  const float* W2 = (const float*)d_in[8];
  const float* W_mlp = (const float*)d_in[9];
  const float* b_mlp = (const float*)d_in[10];
  const float* W_dec = (const float*)d_in[11];
  const float* b_dec = (const float*)d_in[12];
  float* out = (float*)d_out;

  char* ws = (char*)d_ws;
  size_t off = 0;
  auto take = [&](size_t bytes) -> char* {
    char* p = ws + off;
    off = (off + bytes + 255) & ~(size_t)255;
    return p;
  };
  unsigned short* outb = (unsigned short*)take((size_t)B_ * T_ * 2048 * 2);     // 67.1 MB
  unsigned short* hpub = (unsigned short*)take((size_t)2 * T_ * 2 * 16384 * 2); // 67.1 MB
  unsigned short* xb = (unsigned short*)take((size_t)16384 * KE_ * 2);          // 12.6 MB
  unsigned short* wihb = (unsigned short*)take((size_t)8192 * KE_ * 2);         // 6.3 MB
  unsigned short* w1b = (unsigned short*)take((size_t)AC_ * 2048 * 2);          // 1.6 MB
  unsigned short* wmlpb = (unsigned short*)take((size_t)MH_ * FEAT_ * 2);       // 62.9 MB
  unsigned short* th1 = (unsigned short*)take((size_t)16384 * AC_ * 2);         // 12.6 MB
  float* abuf = (float*)take((size_t)B_ * R_ * T_ * 4);                         // 2.0 MB
  unsigned short* mbuf = (unsigned short*)take((size_t)B_ * FEAT_ * 2);         // 3.9 MB
  float* penp = (float*)take(B_ * 4);
  float* hid = (float*)take((size_t)B_ * MH_ * 4);

  if (off > ws_size) {  // unambiguous failure signal: NaN output
    hipMemsetAsync(d_out, 0xFF, (size_t)out_size * 4, stream);
    return;
  }

  // sentinel-init hpub: 0xFFFF bf16 has bit14 set => "unwritten" marker
  hipMemsetAsync(hpub, 0xFF, (size_t)2 * T_ * 2 * 16384 * 2, stream);
  hipMemsetAsync(hid, 0, (size_t)B_ * MH_ * 4, stream);

  k0_prep<<<2048, 256, 0, stream>>>(inp, W_emb, W_ih, W1, W_mlp, xb, wihb, w1b, wmlpb);
  k2_rnn<<<256, 256, 0, stream>>>(W_hh, wihb, xb, b_ih, b_hh, outb, hpub);
  k3_s1<<<512, 256, 0, stream>>>(outb, w1b, th1);
  k4_s2<<<2048, 256, 0, stream>>>(th1, W2, abuf);
  k5_sm<<<240, 256, 0, stream>>>(abuf, lens);
  k6_m<<<512, 256, 0, stream>>>(abuf, outb, mbuf);
  k7_pen<<<32, 256, 0, stream>>>(abuf, penp);
  k8_mlp<<<256, 256, 0, stream>>>(wmlpb, mbuf, hid);
  k9_out<<<1, 128, 0, stream>>>(hid, b_mlp, W_dec, b_dec, penp, out);
}

// Round 16
// 2059.249 us; speedup vs baseline: 1.0487x; 1.0487x over previous
//
#include <hip/hip_runtime.h>
#include <stdint.h>

typedef __attribute__((ext_vector_type(8))) short short8;
typedef __attribute__((ext_vector_type(4))) float f32x4;
typedef __attribute__((ext_vector_type(4))) unsigned int u32x4;

#define B_    32
#define T_    512
#define E_    300
#define KE_   384     // padded embed K (4-wave x 96 split)
#define H_    1024
#define G4_   4096
#define R_    30
#define AD_   350
#define AC_   384
#define MH_   512
#define FEAT_ 61440
#define NU_   16      // hidden units per (dir,w) group
#define DTICK 16ull   // pacing delta: ~0.64us @ 25MHz RTC

__device__ __forceinline__ unsigned short f2bu(float f) {
  unsigned int x = __builtin_bit_cast(unsigned int, f);
  x += 0x7fffu + ((x >> 16) & 1u);
  return (unsigned short)(x >> 16);
}
__device__ __forceinline__ float b2f(unsigned short u) {
  return __builtin_bit_cast(float, (unsigned int)u << 16);
}
__device__ __forceinline__ float sigm(float x) {
  return __builtin_amdgcn_rcpf(1.f + __expf(-x));
}
__device__ __forceinline__ float tanh_fast(float x) {
  return 1.f - 2.f * __builtin_amdgcn_rcpf(1.f + __expf(2.f * x));
}

// 8x dwordx4 gather issue (no waitcnt): 2 bases x 4 imm offsets (ktl steps)
#define BULK8G_ISS(b0p, b1p, FL)                                                \
  asm volatile(                                                                 \
      "global_load_dwordx4 %0, %8, off " FL "\n\t"                              \
      "global_load_dwordx4 %1, %8, off offset:1024 " FL "\n\t"                  \
      "global_load_dwordx4 %2, %8, off offset:2048 " FL "\n\t"                  \
      "global_load_dwordx4 %3, %8, off offset:3072 " FL "\n\t"                  \
      "global_load_dwordx4 %4, %9, off " FL "\n\t"                              \
      "global_load_dwordx4 %5, %9, off offset:1024 " FL "\n\t"                  \
      "global_load_dwordx4 %6, %9, off offset:2048 " FL "\n\t"                  \
      "global_load_dwordx4 %7, %9, off offset:3072 " FL                         \
      : "=&v"(q0), "=&v"(q1), "=&v"(q2), "=&v"(q3),                             \
        "=&v"(q4), "=&v"(q5), "=&v"(q6), "=&v"(q7)                              \
      : "v"(b0p), "v"(b1p)                                                      \
      : "memory")

#define BULK8G(b0p, b1p, FL)                                                    \
  do {                                                                          \
    BULK8G_ISS(b0p, b1p, FL);                                                   \
    asm volatile("s_waitcnt vmcnt(0)" ::: "memory");                            \
    __builtin_amdgcn_sched_barrier(0);                                          \
  } while (0)

// validate: any bf16 half with bit14 set => sentinel/unwritten
#define VAL8(BAD)                                                               \
  {                                                                             \
    u32x4 o01 = q0 | q1, o23 = q2 | q3, o45 = q4 | q5, o67 = q6 | q7;           \
    u32x4 ov4 = (o01 | o23) | (o45 | o67);                                      \
    unsigned ovv = (ov4[0] | ov4[1]) | (ov4[2] | ov4[3]);                       \
    BAD = (ovv & 0x40004000u) != 0;                                             \
  }

// ---------------------------------------------------------------------------
// K0: cast/pad to bf16: xb[16384][384], wihb[8192][384], w1b[384][2048],
//     wmlpb[512][61440]
// ---------------------------------------------------------------------------
__global__ void k0_prep(const int* __restrict__ inp, const float* __restrict__ W_emb,
                        const float* __restrict__ W_ih, const float* __restrict__ W1,
                        const float* __restrict__ W_mlp,
                        unsigned short* __restrict__ xb, unsigned short* __restrict__ wihb,
                        unsigned short* __restrict__ w1b, unsigned short* __restrict__ wmlpb) {
  const int N1 = 16384 * KE_;
  const int N2 = 8192 * KE_;
  const int N3 = AC_ * 2048;
  const int N4 = MH_ * FEAT_;
  const int NT = N1 + N2 + N3 + N4;
  for (int i = blockIdx.x * blockDim.x + threadIdx.x; i < NT; i += gridDim.x * blockDim.x) {
    if (i < N1) {
      int row = i / KE_, e = i - row * KE_;
      float v = (e < E_) ? W_emb[(size_t)inp[row] * E_ + e] : 0.f;
      xb[i] = f2bu(v);
    } else if (i < N1 + N2) {
      int j = i - N1;
      int rw = j / KE_, e = j - rw * KE_;
      float v = (e < E_) ? W_ih[(size_t)rw * E_ + e] : 0.f;
      wihb[j] = f2bu(v);
    } else if (i < N1 + N2 + N3) {
      int j = i - N1 - N2;
      int a = j >> 11, k = j & 2047;
      float v = (a < AD_) ? W1[(size_t)a * 2048 + k] : 0.f;
      w1b[j] = f2bu(v);
    } else {
      int j = i - N1 - N2 - N3;
      wmlpb[j] = f2bu(W_mlp[j]);
    }
  }
}

// ---------------------------------------------------------------------------
// K2 v16 (= v14, proven best): batch-split swarm, 256 WGs = dir2 x w64 x bh2.
//   Step order: x-GEMM (xbf RT) -> pace (hidden under x-GEMM) -> gather
//   issue+wait -> validate -> h-MFMA.  Gather issues ~0.7us after anchor:
//   safely past producer visibility (zero validation failures), arrival
//   ~2.2us; cadence ~3.1us/step, near the rendezvous-latency floor.
// ---------------------------------------------------------------------------
__global__ __launch_bounds__(256, 1) void k2_rnn(const float* __restrict__ Whh,
                                                 const unsigned short* __restrict__ wihb,
                                                 const unsigned short* __restrict__ xb,
                                                 const float* __restrict__ b_ih,
                                                 const float* __restrict__ b_hh,
                                                 unsigned short* __restrict__ outb,
                                                 unsigned short* __restrict__ hpub) {
  const int dir = blockIdx.x >> 7;
  const int w = (blockIdx.x >> 1) & 63;
  const int bh = blockIdx.x & 1;
  const int tid = threadIdx.x;
  const int wid = tid >> 6, lane = tid & 63;
  const int l15 = lane & 15, lg = lane >> 4;

  __shared__ float Gp[4][4][16][17];               // [wave][gate][batch16][unit+pad]
  __shared__ __align__(16) unsigned short htmp[16][16];

  // ---- preload W_hh K-quarter as bf16 A-frags (units 0..15, 4 gates) ---
  short8 afr[4][8];
  {
    const int kq = wid << 8;
#pragma unroll
    for (int g = 0; g < 4; ++g) {
      const float* wp = Whh + ((size_t)dir * G4_ + g * H_ + w * NU_ + l15) * H_ + kq + lg * 8;
#pragma unroll
      for (int ktl = 0; ktl < 8; ++ktl) {
        float4 f0 = *(const float4*)(wp + ktl * 32);
        float4 f1 = *(const float4*)(wp + ktl * 32 + 4);
        short8 s;
        s[0] = (short)f2bu(f0.x); s[1] = (short)f2bu(f0.y);
        s[2] = (short)f2bu(f0.z); s[3] = (short)f2bu(f0.w);
        s[4] = (short)f2bu(f1.x); s[5] = (short)f2bu(f1.y);
        s[6] = (short)f2bu(f1.z); s[7] = (short)f2bu(f1.w);
        afr[g][ktl] = s;
      }
    }
  }

  // ---- preload W_ih K-slice (96 of 384) as bf16 A-frags ----------------
  const int kqx = wid * 96;
  short8 axr[4][3];
#pragma unroll
  for (int g = 0; g < 4; ++g) {
    const unsigned short* xp = wihb + ((size_t)dir * G4_ + g * H_ + w * NU_ + l15) * KE_ + kqx + lg * 8;
#pragma unroll
    for (int kt = 0; kt < 3; ++kt) axr[g][kt] = *(const short8*)(xp + kt * 32);
  }

  const int u = tid >> 4;    // activation role: unit 0..15
  const int b = tid & 15;    // activation role: batch-within-half 0..15

  float bsum[4];
#pragma unroll
  for (int g = 0; g < 4; ++g) {
    int row = dir * G4_ + g * H_ + w * NU_ + u;
    bsum[g] = b_ih[row] + b_hh[row];
  }

  // gather/poll offsets within a (dir,t,bh) slot of 64 chunks x 256 ushorts
  const size_t hlane = (size_t)(wid * 16 + (lg >> 1)) * 256 + l15 * 16 + (lg & 1) * 8;
  const size_t hpoll = (size_t)(wid * 16 + (lane & 15)) * 256;

  float cst = 0.f;
  unsigned long long pprev = __builtin_amdgcn_s_memrealtime();

#pragma unroll 1
  for (int s = 0; s < T_; ++s) {
    const int t = dir ? (T_ - 1 - s) : s;

    f32x4 acc[4];
#pragma unroll
    for (int g = 0; g < 4; ++g) acc[g] = (f32x4){0.f, 0.f, 0.f, 0.f};

    // -- x-GEMM (12 MFMAs): cols = batch bh*16+l15; hides the pace window -
    {
      short8 xbf[3];
#pragma unroll
      for (int kt = 0; kt < 3; ++kt)
        xbf[kt] = *(const short8*)(xb + ((size_t)(bh * 16 + l15) * T_ + t) * KE_ + kqx + kt * 32 + lg * 8);
#pragma unroll
      for (int kt = 0; kt < 3; ++kt)
#pragma unroll
        for (int g = 0; g < 4; ++g)
          acc[g] = __builtin_amdgcn_mfma_f32_16x16x32_bf16(axr[g][kt], xbf[kt], acc[g], 0, 0, 0);
    }
    __builtin_amdgcn_sched_barrier(0);

    if (s > 0) {
      const int tsrc = dir ? t + 1 : t - 1;
      const unsigned short* hbase = hpub + ((size_t)(dir * T_ + tsrc) * 2 + bh) * 16384;
      const unsigned short* B0 = hbase + hlane;
      const unsigned short* B1 = B0 + 4096;      // +8 chunks (ktl 4..7)
      u32x4 q0, q1, q2, q3, q4, q5, q6, q7;

      // -- pace: spin on scalar clock until own prev publish + DTICK ------
      {
        unsigned long long tgt = pprev + DTICK;
        unsigned long long now;
        do { now = __builtin_amdgcn_s_memrealtime(); } while (now < tgt);
      }

      // -- speculative payload: 8x dwordx4 sc0 gather, validate -----------
      BULK8G(B0, B1, "sc0");
      bool bad; VAL8(bad);
      if (__builtin_expect(bad, 0)) {
        // backstop: thin-poll this wave's 16 producer chunks, then retry
        const unsigned short* sp = hbase + hpoll;
        unsigned v;
        int guard = 0;
        for (;;) {
          asm volatile("global_load_dword %0, %1, off sc0 sc1\n\ts_waitcnt vmcnt(0)"
                       : "=v"(v) : "v"(sp) : "memory");
          if (__all(!(v & 0x40004000u))) break;
          if (++guard > 50000) break;   // hang safety; never trips co-resident
        }
        int g2 = 0;
        do {
          BULK8G(B0, B1, "sc0 sc1");
          VAL8(bad);
        } while (bad && ++g2 < 50000);
      }

      short8 bf[8];
      bf[0] = __builtin_bit_cast(short8, q0); bf[1] = __builtin_bit_cast(short8, q1);
      bf[2] = __builtin_bit_cast(short8, q2); bf[3] = __builtin_bit_cast(short8, q3);
      bf[4] = __builtin_bit_cast(short8, q4); bf[5] = __builtin_bit_cast(short8, q5);
      bf[6] = __builtin_bit_cast(short8, q6); bf[7] = __builtin_bit_cast(short8, q7);

#pragma unroll
      for (int ktl = 0; ktl < 8; ++ktl)
#pragma unroll
        for (int g = 0; g < 4; ++g)
          acc[g] = __builtin_amdgcn_mfma_f32_16x16x32_bf16(afr[g][ktl], bf[ktl], acc[g], 0, 0, 0);
    }

    // -- write K-partial sums to LDS -------------------------------------
#pragma unroll
    for (int g = 0; g < 4; ++g)
#pragma unroll
      for (int j = 0; j < 4; ++j)
        Gp[wid][g][l15][lg * 4 + j] = acc[g][j];
    __syncthreads();

    // -- activations: thread handles (u, b) ------------------------------
    {
      float gi = Gp[0][0][b][u] + Gp[1][0][b][u] + Gp[2][0][b][u] + Gp[3][0][b][u] + bsum[0];
      float gf = Gp[0][1][b][u] + Gp[1][1][b][u] + Gp[2][1][b][u] + Gp[3][1][b][u] + bsum[1];
      float gg = Gp[0][2][b][u] + Gp[1][2][b][u] + Gp[2][2][b][u] + Gp[3][2][b][u] + bsum[2];
      float go = Gp[0][3][b][u] + Gp[1][3][b][u] + Gp[2][3][b][u] + Gp[3][3][b][u] + bsum[3];
      cst = sigm(gf) * cst + sigm(gi) * tanh_fast(gg);
      float hv = sigm(go) * tanh_fast(cst);
      htmp[b][u] = f2bu(hv);
    }
    __syncthreads();

    // -- record anchor; wave 0 publishes chunk (512B contiguous) + outb --
    pprev = __builtin_amdgcn_s_memrealtime();
    if (tid < 64) {
      int bb = tid >> 2, q = tid & 3;
      uint2 v = *(const uint2*)&htmp[bb][q * 4];
      unsigned short* hp = hpub + ((size_t)(dir * T_ + t) * 2 + bh) * 16384 + (size_t)w * 256 + bb * 16 + q * 4;
      asm volatile("global_store_dwordx2 %0, %1, off sc0 sc1" :: "v"(hp), "v"(v) : "memory");
      *(uint2*)(outb + ((size_t)(bh * 16 + bb) * T_ + t) * 2048 + dir * H_ + w * NU_ + q * 4) = v;
    }
  }
}

// ---------------------------------------------------------------------------
// K3: th1[row][a] = tanh( out[row][:] . W1b[a][:] )
// ---------------------------------------------------------------------------
__global__ __launch_bounds__(256, 1) void k3_s1(const unsigned short* __restrict__ outb,
                                                const unsigned short* __restrict__ w1b,
                                                unsigned short* __restrict__ th1) {
  const int rb = blockIdx.x;
  const int wid = threadIdx.x >> 6, lane = threadIdx.x & 63;
  const int m = wid & 1, nh = wid >> 1;
  const int l15 = lane & 15, lg = lane >> 4;

  f32x4 acc[12];
#pragma unroll
  for (int nt = 0; nt < 12; ++nt) acc[nt] = (f32x4){0.f, 0.f, 0.f, 0.f};

  const unsigned short* arow = outb + ((size_t)rb * 32 + m * 16 + l15) * 2048;
  for (int kt = 0; kt < 64; ++kt) {
    short8 af = *(const short8*)(arow + kt * 32 + lg * 8);
#pragma unroll
    for (int nt = 0; nt < 12; ++nt) {
      int col = nh * 192 + nt * 16 + l15;
      short8 bf = *(const short8*)(w1b + (size_t)col * 2048 + kt * 32 + lg * 8);
      acc[nt] = __builtin_amdgcn_mfma_f32_16x16x32_bf16(af, bf, acc[nt], 0, 0, 0);
    }
  }
#pragma unroll
  for (int nt = 0; nt < 12; ++nt) {
#pragma unroll
    for (int j = 0; j < 4; ++j) {
      int row = rb * 32 + m * 16 + lg * 4 + j;
      int col = nh * 192 + nt * 16 + l15;
      th1[(size_t)row * AC_ + col] = f2bu(tanh_fast(acc[nt][j]));
    }
  }
}

// ---------------------------------------------------------------------------
// K4: abuf[b][r][t] = th1[row][:350] . W2[r][:350]
// ---------------------------------------------------------------------------
__global__ void k4_s2(const unsigned short* __restrict__ th1, const float* __restrict__ W2,
                      float* __restrict__ abuf) {
  int idx = blockIdx.x * 256 + threadIdx.x;
  int row = idx >> 5, r = idx & 31;
  if (r >= R_) return;
  const unsigned short* tp = th1 + (size_t)row * AC_;
  const float* wp = W2 + r * AD_;
  float acc = 0.f;
  for (int a = 0; a < AD_; ++a) acc = fmaf(b2f(tp[a]), wp[a], acc);
  int b = row >> 9, t = row & 511;
  abuf[((size_t)b * R_ + r) * T_ + t] = acc;
}

// ---------------------------------------------------------------------------
// K5: masked softmax over t (in place).  One wave per (b,r).
// ---------------------------------------------------------------------------
__global__ void k5_sm(float* __restrict__ abuf, const int* __restrict__ lens) {
  int wv = blockIdx.x * 4 + (threadIdx.x >> 6);
  int lane = threadIdx.x & 63;
  if (wv >= B_ * R_) return;
  int b = wv / R_, r = wv % R_;
  int len = lens[b];
  float* row = abuf + ((size_t)b * R_ + r) * T_;
  float v[8];
  float mx = -1e30f;
#pragma unroll
  for (int i = 0; i < 8; ++i) {
    int t = lane + i * 64;
    float x = (t < len) ? row[t] : -1e30f;
    v[i] = x;
    mx = fmaxf(mx, x);
  }
#pragma unroll
  for (int o = 32; o > 0; o >>= 1) mx = fmaxf(mx, __shfl_xor(mx, o));
  float sum = 0.f;
#pragma unroll
  for (int i = 0; i < 8; ++i) {
    float e = (v[i] > -1e29f) ? __expf(v[i] - mx) : 0.f;
    v[i] = e;
    sum += e;
  }
#pragma unroll
  for (int o = 32; o > 0; o >>= 1) sum += __shfl_xor(sum, o);
  float inv = 1.f / sum;
#pragma unroll
  for (int i = 0; i < 8; ++i) row[lane + i * 64] = v[i] * inv;
}

// ---------------------------------------------------------------------------
// K6: M[b][r][h] = sum_t A[b][r][t] * out[b][t][h].  Writes mbuf as bf16.
// ---------------------------------------------------------------------------
__global__ __launch_bounds__(256) void k6_m(const float* __restrict__ abuf,
                                            const unsigned short* __restrict__ outb,
                                            unsigned short* __restrict__ mbuf) {
  int b = blockIdx.x >> 4, hb = blockIdx.x & 15;
  __shared__ float As[R_ * T_];
  for (int i = threadIdx.x; i < R_ * T_; i += 256) As[i] = abuf[(size_t)b * R_ * T_ + i];
  __syncthreads();
  int h = threadIdx.x & 127, rh = threadIdx.x >> 7;
  float acc[15];
#pragma unroll
  for (int rr = 0; rr < 15; ++rr) acc[rr] = 0.f;
  const unsigned short* op = outb + (size_t)b * T_ * 2048 + hb * 128 + h;
  for (int t = 0; t < T_; ++t) {
    float vv = b2f(op[(size_t)t * 2048]);
#pragma unroll
    for (int rr = 0; rr < 15; ++rr) acc[rr] = fmaf(As[(rh * 15 + rr) * T_ + t], vv, acc[rr]);
  }
#pragma unroll
  for (int rr = 0; rr < 15; ++rr)
    mbuf[(size_t)b * FEAT_ + (size_t)(rh * 15 + rr) * 2048 + hb * 128 + h] = f2bu(acc[rr]);
}

// ---------------------------------------------------------------------------
// K7: per-sample penalty partial: ||A A^T - I||_F^2.
// ---------------------------------------------------------------------------
__global__ __launch_bounds__(256) void k7_pen(const float* __restrict__ abuf,
                                              float* __restrict__ penp) {
  int b = blockIdx.x;
  __shared__ float As[R_ * 515];
  __shared__ float red[256];
  for (int i = threadIdx.x; i < R_ * T_; i += 256) {
    int r = i >> 9, t = i & 511;
    As[r * 515 + t] = abuf[(size_t)b * R_ * T_ + i];
  }
  __syncthreads();
  float psum = 0.f;
  for (int p = threadIdx.x; p < R_ * R_; p += 256) {
    int r = p / R_, s = p % R_;
    const float* pr = As + r * 515;
    const float* ps = As + s * 515;
    float d = 0.f;
    for (int t = 0; t < T_; ++t) d = fmaf(pr[t], ps[t], d);
    d -= (r == s) ? 1.f : 0.f;
    psum += d * d;
  }
  red[threadIdx.x] = psum;
  __syncthreads();
  for (int o = 128; o > 0; o >>= 1) {
    if (threadIdx.x < o) red[threadIdx.x] += red[threadIdx.x + o];
    __syncthreads();
  }
  if (threadIdx.x == 0) penp[b] = red[0];
}

// ---------------------------------------------------------------------------
// K8 v2: hidsum[b][m] += wmlpb[m-tile][k-tile] . mbuf[b][k-tile]  (MFMA)
// ---------------------------------------------------------------------------
__global__ __launch_bounds__(256, 1) void k8_mlp(const unsigned short* __restrict__ wmlpb,
                                                 const unsigned short* __restrict__ mbuf,
                                                 float* __restrict__ hid) {
  const int mblk = blockIdx.x >> 4, kblk = blockIdx.x & 15;
  const int wid = threadIdx.x >> 6, lane = threadIdx.x & 63;
  const int l15 = lane & 15, lg = lane >> 4;
  const int kq = kblk * 3840 + wid * 960;

  f32x4 acc[2][2];
#pragma unroll
  for (int i = 0; i < 2; ++i)
#pragma unroll
    for (int j = 0; j < 2; ++j) acc[i][j] = (f32x4){0.f, 0.f, 0.f, 0.f};

  const unsigned short* ap0 = wmlpb + (size_t)(mblk * 32 + l15) * FEAT_ + kq + lg * 8;
  const unsigned short* ap1 = ap0 + (size_t)16 * FEAT_;
  const unsigned short* bp0 = mbuf + (size_t)l15 * FEAT_ + kq + lg * 8;
  const unsigned short* bp1 = bp0 + (size_t)16 * FEAT_;
  for (int kt = 0; kt < 30; ++kt) {
    short8 a0 = *(const short8*)(ap0 + kt * 32);
    short8 a1 = *(const short8*)(ap1 + kt * 32);
    short8 b0 = *(const short8*)(bp0 + kt * 32);
    short8 b1 = *(const short8*)(bp1 + kt * 32);
    acc[0][0] = __builtin_amdgcn_mfma_f32_16x16x32_bf16(a0, b0, acc[0][0], 0, 0, 0);
    acc[0][1] = __builtin_amdgcn_mfma_f32_16x16x32_bf16(a0, b1, acc[0][1], 0, 0, 0);
    acc[1][0] = __builtin_amdgcn_mfma_f32_16x16x32_bf16(a1, b0, acc[1][0], 0, 0, 0);
    acc[1][1] = __builtin_amdgcn_mfma_f32_16x16x32_bf16(a1, b1, acc[1][1], 0, 0, 0);
  }

  __shared__ float red[4][32][33];
#pragma unroll
  for (int mi = 0; mi < 2; ++mi)
#pragma unroll
    for (int ni = 0; ni < 2; ++ni)
#pragma unroll
      for (int j = 0; j < 4; ++j)
        red[wid][mi * 16 + lg * 4 + j][ni * 16 + l15] = acc[mi][ni][j];
  __syncthreads();

  int m = threadIdx.x >> 3, b4 = (threadIdx.x & 7) * 4;
#pragma unroll
  for (int k = 0; k < 4; ++k) {
    int bb = b4 + k;
    float s = red[0][m][bb] + red[1][m][bb] + red[2][m][bb] + red[3][m][bb];
    atomicAdd(&hid[(size_t)bb * MH_ + mblk * 32 + m], s);
  }
}

// ---------------------------------------------------------------------------
// K9: decoded = softmax( relu(hid+b_mlp) @ W_dec^T + b_dec ); penal = mean.
// ---------------------------------------------------------------------------
__global__ void k9_out(const float* __restrict__ hid, const float* __restrict__ b_mlp,
                       const float* __restrict__ W_dec, const float* __restrict__ b_dec,
                       const float* __restrict__ penp, float* __restrict__ out) {
  int tid = threadIdx.x;
  if (tid < 64) {
    int b = tid >> 1, c = tid & 1;
    const float* hp = hid + (size_t)b * MH_;
    const float* wp = W_dec + (size_t)c * MH_;
    float acc = b_dec[c];
    for (int k = 0; k < MH_; ++k) {
      float hk = fmaxf(hp[k] + b_mlp[k], 0.f);
      acc = fmaf(hk, wp[k], acc);
    }
    float other = __shfl_xor(acc, 1);
    float mx = fmaxf(acc, other);
    float e = __expf(acc - mx), eo = __expf(other - mx);
    out[b * 2 + c] = e / (e + eo);
  } else if (tid == 64) {
    float s = 0.f;
    for (int b = 0; b < B_; ++b) s += penp[b];
    out[64] = s * (1.f / 32.f);
  }
}

// ---------------------------------------------------------------------------
extern "C" void kernel_launch(void* const* d_in, const int* in_sizes, int n_in,
                              void* d_out, int out_size, void* d_ws, size_t ws_size,
                              hipStream_t stream) {
  const int* inp = (const int*)d_in[0];
  const int* lens = (const int*)d_in[1];
  const float* W_emb = (const float*)d_in[2];
  const float* W_ih = (const float*)d_in[3];
  const float* W_hh = (const float*)d_in[4];
  const float* b_ih = (const float*)d_in[5];
  const float* b_hh = (const float*)d_in[6];
  const float* W1 = (const float*)d_in[7];
  const float* W2 = (const float*)d_in[8];
  const float* W_mlp = (const float*)d_in[9];
  const float* b_mlp = (const float*)d_in[10];
  const float* W_dec = (const float*)d_in[11];
  const float* b_dec = (const float*)d_in[12];
  float* out = (float*)d_out;

  char* ws = (char*)d_ws;
  size_t off = 0;
  auto take = [&](size_t bytes) -> char* {
    char* p = ws + off;
    off = (off + bytes + 255) & ~(size_t)255;
    return p;
  };
  unsigned short* outb = (unsigned short*)take((size_t)B_ * T_ * 2048 * 2);     // 67.1 MB
  unsigned short* hpub = (unsigned short*)take((size_t)2 * T_ * 2 * 16384 * 2); // 67.1 MB
  unsigned short* xb = (unsigned short*)take((size_t)16384 * KE_ * 2);          // 12.6 MB
  unsigned short* wihb = (unsigned short*)take((size_t)8192 * KE_ * 2);         // 6.3 MB
  unsigned short* w1b = (unsigned short*)take((size_t)AC_ * 2048 * 2);          // 1.6 MB
  unsigned short* wmlpb = (unsigned short*)take((size_t)MH_ * FEAT_ * 2);       // 62.9 MB
  unsigned short* th1 = (unsigned short*)take((size_t)16384 * AC_ * 2);         // 12.6 MB
  float* abuf = (float*)take((size_t)B_ * R_ * T_ * 4);                         // 2.0 MB
  unsigned short* mbuf = (unsigned short*)take((size_t)B_ * FEAT_ * 2);         // 3.9 MB
  float* penp = (float*)take(B_ * 4);
  float* hid = (float*)take((size_t)B_ * MH_ * 4);

  if (off > ws_size) {  // unambiguous failure signal: NaN output
    hipMemsetAsync(d_out, 0xFF, (size_t)out_size * 4, stream);
    return;
  }

  // sentinel-init hpub: 0xFFFF bf16 has bit14 set => "unwritten" marker
  hipMemsetAsync(hpub, 0xFF, (size_t)2 * T_ * 2 * 16384 * 2, stream);
  hipMemsetAsync(hid, 0, (size_t)B_ * MH_ * 4, stream);

  k0_prep<<<2048, 256, 0, stream>>>(inp, W_emb, W_ih, W1, W_mlp, xb, wihb, w1b, wmlpb);
  k2_rnn<<<256, 256, 0, stream>>>(W_hh, wihb, xb, b_ih, b_hh, outb, hpub);
  k3_s1<<<512, 256, 0, stream>>>(outb, w1b, th1);
  k4_s2<<<2048, 256, 0, stream>>>(th1, W2, abuf);
  k5_sm<<<240, 256, 0, stream>>>(abuf, lens);
  k6_m<<<512, 256, 0, stream>>>(abuf, outb, mbuf);
  k7_pen<<<32, 256, 0, stream>>>(abuf, penp);
  k8_mlp<<<256, 256, 0, stream>>>(wmlpb, mbuf, hid);
  k9_out<<<1, 128, 0, stream>>>(hid, b_mlp, W_dec, b_dec, penp, out);
}

// Round 17
// 2031.442 us; speedup vs baseline: 1.0630x; 1.0137x over previous
//
#include <hip/hip_runtime.h>
#include <stdint.h>

typedef __attribute__((ext_vector_type(8))) short short8;
typedef __attribute__((ext_vector_type(4))) float f32x4;
typedef __attribute__((ext_vector_type(4))) unsigned int u32x4;

#define B_    32
#define T_    512
#define E_    300
#define KE_   384     // padded embed K (4-wave x 96 split)
#define H_    1024
#define G4_   4096
#define R_    30
#define AD_   350
#define AC_   384
#define MH_   512
#define FEAT_ 61440
#define NU_   16      // hidden units per (dir,w) group
#define DTICK 16ull   // pacing delta: ~0.64us @ 25MHz RTC

__device__ __forceinline__ unsigned short f2bu(float f) {
  unsigned int x = __builtin_bit_cast(unsigned int, f);
  x += 0x7fffu + ((x >> 16) & 1u);
  return (unsigned short)(x >> 16);
}
__device__ __forceinline__ float b2f(unsigned short u) {
  return __builtin_bit_cast(float, (unsigned int)u << 16);
}
__device__ __forceinline__ float sigm(float x) {
  return __builtin_amdgcn_rcpf(1.f + __expf(-x));
}
__device__ __forceinline__ float tanh_fast(float x) {
  return 1.f - 2.f * __builtin_amdgcn_rcpf(1.f + __expf(2.f * x));
}

// 8x dwordx4 gather issue (no waitcnt): 2 bases x 4 imm offsets (ktl steps)
#define BULK8G_ISS(b0p, b1p, FL)                                                \
  asm volatile(                                                                 \
      "global_load_dwordx4 %0, %8, off " FL "\n\t"                              \
      "global_load_dwordx4 %1, %8, off offset:1024 " FL "\n\t"                  \
      "global_load_dwordx4 %2, %8, off offset:2048 " FL "\n\t"                  \
      "global_load_dwordx4 %3, %8, off offset:3072 " FL "\n\t"                  \
      "global_load_dwordx4 %4, %9, off " FL "\n\t"                              \
      "global_load_dwordx4 %5, %9, off offset:1024 " FL "\n\t"                  \
      "global_load_dwordx4 %6, %9, off offset:2048 " FL "\n\t"                  \
      "global_load_dwordx4 %7, %9, off offset:3072 " FL                         \
      : "=&v"(q0), "=&v"(q1), "=&v"(q2), "=&v"(q3),                             \
        "=&v"(q4), "=&v"(q5), "=&v"(q6), "=&v"(q7)                              \
      : "v"(b0p), "v"(b1p)                                                      \
      : "memory")

#define BULK8G(b0p, b1p, FL)                                                    \
  do {                                                                          \
    BULK8G_ISS(b0p, b1p, FL);                                                   \
    asm volatile("s_waitcnt vmcnt(0)" ::: "memory");                            \
    __builtin_amdgcn_sched_barrier(0);                                          \
  } while (0)

// validate: any bf16 half with bit14 set => sentinel/unwritten
#define VAL8(BAD)                                                               \
  {                                                                             \
    u32x4 o01 = q0 | q1, o23 = q2 | q3, o45 = q4 | q5, o67 = q6 | q7;           \
    u32x4 ov4 = (o01 | o23) | (o45 | o67);                                      \
    unsigned ovv = (ov4[0] | ov4[1]) | (ov4[2] | ov4[3]);                       \
    BAD = (ovv & 0x40004000u) != 0;                                             \
  }

// ---------------------------------------------------------------------------
// K0: cast/pad to bf16: xb[16384][384], wihb[8192][384], w1b[384][2048]
//     (W_mlp is now consumed fp32 directly by K8)
// ---------------------------------------------------------------------------
__global__ void k0_prep(const int* __restrict__ inp, const float* __restrict__ W_emb,
                        const float* __restrict__ W_ih, const float* __restrict__ W1,
                        unsigned short* __restrict__ xb, unsigned short* __restrict__ wihb,
                        unsigned short* __restrict__ w1b) {
  const int N1 = 16384 * KE_;
  const int N2 = 8192 * KE_;
  const int N3 = AC_ * 2048;
  const int NT = N1 + N2 + N3;
  for (int i = blockIdx.x * blockDim.x + threadIdx.x; i < NT; i += gridDim.x * blockDim.x) {
    if (i < N1) {
      int row = i / KE_, e = i - row * KE_;
      float v = (e < E_) ? W_emb[(size_t)inp[row] * E_ + e] : 0.f;
      xb[i] = f2bu(v);
    } else if (i < N1 + N2) {
      int j = i - N1;
      int rw = j / KE_, e = j - rw * KE_;
      float v = (e < E_) ? W_ih[(size_t)rw * E_ + e] : 0.f;
      wihb[j] = f2bu(v);
    } else {
      int j = i - N1 - N2;
      int a = j >> 11, k = j & 2047;
      float v = (a < AD_) ? W1[(size_t)a * 2048 + k] : 0.f;
      w1b[j] = f2bu(v);
    }
  }
}

// ---------------------------------------------------------------------------
// K2 (v14/v16, proven best -- UNCHANGED): batch-split swarm, 256 WGs.
// ---------------------------------------------------------------------------
__global__ __launch_bounds__(256, 1) void k2_rnn(const float* __restrict__ Whh,
                                                 const unsigned short* __restrict__ wihb,
                                                 const unsigned short* __restrict__ xb,
                                                 const float* __restrict__ b_ih,
                                                 const float* __restrict__ b_hh,
                                                 unsigned short* __restrict__ outb,
                                                 unsigned short* __restrict__ hpub) {
  const int dir = blockIdx.x >> 7;
  const int w = (blockIdx.x >> 1) & 63;
  const int bh = blockIdx.x & 1;
  const int tid = threadIdx.x;
  const int wid = tid >> 6, lane = tid & 63;
  const int l15 = lane & 15, lg = lane >> 4;

  __shared__ float Gp[4][4][16][17];               // [wave][gate][batch16][unit+pad]
  __shared__ __align__(16) unsigned short htmp[16][16];

  // ---- preload W_hh K-quarter as bf16 A-frags (units 0..15, 4 gates) ---
  short8 afr[4][8];
  {
    const int kq = wid << 8;
#pragma unroll
    for (int g = 0; g < 4; ++g) {
      const float* wp = Whh + ((size_t)dir * G4_ + g * H_ + w * NU_ + l15) * H_ + kq + lg * 8;
#pragma unroll
      for (int ktl = 0; ktl < 8; ++ktl) {
        float4 f0 = *(const float4*)(wp + ktl * 32);
        float4 f1 = *(const float4*)(wp + ktl * 32 + 4);
        short8 s;
        s[0] = (short)f2bu(f0.x); s[1] = (short)f2bu(f0.y);
        s[2] = (short)f2bu(f0.z); s[3] = (short)f2bu(f0.w);
        s[4] = (short)f2bu(f1.x); s[5] = (short)f2bu(f1.y);
        s[6] = (short)f2bu(f1.z); s[7] = (short)f2bu(f1.w);
        afr[g][ktl] = s;
      }
    }
  }

  // ---- preload W_ih K-slice (96 of 384) as bf16 A-frags ----------------
  const int kqx = wid * 96;
  short8 axr[4][3];
#pragma unroll
  for (int g = 0; g < 4; ++g) {
    const unsigned short* xp = wihb + ((size_t)dir * G4_ + g * H_ + w * NU_ + l15) * KE_ + kqx + lg * 8;
#pragma unroll
    for (int kt = 0; kt < 3; ++kt) axr[g][kt] = *(const short8*)(xp + kt * 32);
  }

  const int u = tid >> 4;    // activation role: unit 0..15
  const int b = tid & 15;    // activation role: batch-within-half 0..15

  float bsum[4];
#pragma unroll
  for (int g = 0; g < 4; ++g) {
    int row = dir * G4_ + g * H_ + w * NU_ + u;
    bsum[g] = b_ih[row] + b_hh[row];
  }

  // gather/poll offsets within a (dir,t,bh) slot of 64 chunks x 256 ushorts
  const size_t hlane = (size_t)(wid * 16 + (lg >> 1)) * 256 + l15 * 16 + (lg & 1) * 8;
  const size_t hpoll = (size_t)(wid * 16 + (lane & 15)) * 256;

  float cst = 0.f;
  unsigned long long pprev = __builtin_amdgcn_s_memrealtime();

#pragma unroll 1
  for (int s = 0; s < T_; ++s) {
    const int t = dir ? (T_ - 1 - s) : s;

    f32x4 acc[4];
#pragma unroll
    for (int g = 0; g < 4; ++g) acc[g] = (f32x4){0.f, 0.f, 0.f, 0.f};

    // -- x-GEMM (12 MFMAs): cols = batch bh*16+l15; hides the pace window -
    {
      short8 xbf[3];
#pragma unroll
      for (int kt = 0; kt < 3; ++kt)
        xbf[kt] = *(const short8*)(xb + ((size_t)(bh * 16 + l15) * T_ + t) * KE_ + kqx + kt * 32 + lg * 8);
#pragma unroll
      for (int kt = 0; kt < 3; ++kt)
#pragma unroll
        for (int g = 0; g < 4; ++g)
          acc[g] = __builtin_amdgcn_mfma_f32_16x16x32_bf16(axr[g][kt], xbf[kt], acc[g], 0, 0, 0);
    }
    __builtin_amdgcn_sched_barrier(0);

    if (s > 0) {
      const int tsrc = dir ? t + 1 : t - 1;
      const unsigned short* hbase = hpub + ((size_t)(dir * T_ + tsrc) * 2 + bh) * 16384;
      const unsigned short* B0 = hbase + hlane;
      const unsigned short* B1 = B0 + 4096;      // +8 chunks (ktl 4..7)
      u32x4 q0, q1, q2, q3, q4, q5, q6, q7;

      // -- pace: spin on scalar clock until own prev publish + DTICK ------
      {
        unsigned long long tgt = pprev + DTICK;
        unsigned long long now;
        do { now = __builtin_amdgcn_s_memrealtime(); } while (now < tgt);
      }

      // -- speculative payload: 8x dwordx4 sc0 gather, validate -----------
      BULK8G(B0, B1, "sc0");
      bool bad; VAL8(bad);
      if (__builtin_expect(bad, 0)) {
        // backstop: thin-poll this wave's 16 producer chunks, then retry
        const unsigned short* sp = hbase + hpoll;
        unsigned v;
        int guard = 0;
        for (;;) {
          asm volatile("global_load_dword %0, %1, off sc0 sc1\n\ts_waitcnt vmcnt(0)"
                       : "=v"(v) : "v"(sp) : "memory");
          if (__all(!(v & 0x40004000u))) break;
          if (++guard > 50000) break;   // hang safety; never trips co-resident
        }
        int g2 = 0;
        do {
          BULK8G(B0, B1, "sc0 sc1");
          VAL8(bad);
        } while (bad && ++g2 < 50000);
      }

      short8 bf[8];
      bf[0] = __builtin_bit_cast(short8, q0); bf[1] = __builtin_bit_cast(short8, q1);
      bf[2] = __builtin_bit_cast(short8, q2); bf[3] = __builtin_bit_cast(short8, q3);
      bf[4] = __builtin_bit_cast(short8, q4); bf[5] = __builtin_bit_cast(short8, q5);
      bf[6] = __builtin_bit_cast(short8, q6); bf[7] = __builtin_bit_cast(short8, q7);

#pragma unroll
      for (int ktl = 0; ktl < 8; ++ktl)
#pragma unroll
        for (int g = 0; g < 4; ++g)
          acc[g] = __builtin_amdgcn_mfma_f32_16x16x32_bf16(afr[g][ktl], bf[ktl], acc[g], 0, 0, 0);
    }

    // -- write K-partial sums to LDS -------------------------------------
#pragma unroll
    for (int g = 0; g < 4; ++g)
#pragma unroll
      for (int j = 0; j < 4; ++j)
        Gp[wid][g][l15][lg * 4 + j] = acc[g][j];
    __syncthreads();

    // -- activations: thread handles (u, b) ------------------------------
    {
      float gi = Gp[0][0][b][u] + Gp[1][0][b][u] + Gp[2][0][b][u] + Gp[3][0][b][u] + bsum[0];
      float gf = Gp[0][1][b][u] + Gp[1][1][b][u] + Gp[2][1][b][u] + Gp[3][1][b][u] + bsum[1];
      float gg = Gp[0][2][b][u] + Gp[1][2][b][u] + Gp[2][2][b][u] + Gp[3][2][b][u] + bsum[2];
      float go = Gp[0][3][b][u] + Gp[1][3][b][u] + Gp[2][3][b][u] + Gp[3][3][b][u] + bsum[3];
      cst = sigm(gf) * cst + sigm(gi) * tanh_fast(gg);
      float hv = sigm(go) * tanh_fast(cst);
      htmp[b][u] = f2bu(hv);
    }
    __syncthreads();

    // -- record anchor; wave 0 publishes chunk (512B contiguous) + outb --
    pprev = __builtin_amdgcn_s_memrealtime();
    if (tid < 64) {
      int bb = tid >> 2, q = tid & 3;
      uint2 v = *(const uint2*)&htmp[bb][q * 4];
      unsigned short* hp = hpub + ((size_t)(dir * T_ + t) * 2 + bh) * 16384 + (size_t)w * 256 + bb * 16 + q * 4;
      asm volatile("global_store_dwordx2 %0, %1, off sc0 sc1" :: "v"(hp), "v"(v) : "memory");
      *(uint2*)(outb + ((size_t)(bh * 16 + bb) * T_ + t) * 2048 + dir * H_ + w * NU_ + q * 4) = v;
    }
  }
}

// ---------------------------------------------------------------------------
// K3 v2 (fused k3+k4): per 32-row block, th1 tile stays in LDS; then the
//   960 (row, r) attention dots s2 = th1 . W2 are computed in-block.
// ---------------------------------------------------------------------------
__global__ __launch_bounds__(256, 1) void k3_s1(const unsigned short* __restrict__ outb,
                                                const unsigned short* __restrict__ w1b,
                                                const float* __restrict__ W2,
                                                float* __restrict__ abuf) {
  const int rb = blockIdx.x;
  const int wid = threadIdx.x >> 6, lane = threadIdx.x & 63;
  const int m = wid & 1, nh = wid >> 1;
  const int l15 = lane & 15, lg = lane >> 4;

  __shared__ unsigned short th_l[32][392];

  f32x4 acc[12];
#pragma unroll
  for (int nt = 0; nt < 12; ++nt) acc[nt] = (f32x4){0.f, 0.f, 0.f, 0.f};

  const unsigned short* arow = outb + ((size_t)rb * 32 + m * 16 + l15) * 2048;
  for (int kt = 0; kt < 64; ++kt) {
    short8 af = *(const short8*)(arow + kt * 32 + lg * 8);
#pragma unroll
    for (int nt = 0; nt < 12; ++nt) {
      int col = nh * 192 + nt * 16 + l15;
      short8 bf = *(const short8*)(w1b + (size_t)col * 2048 + kt * 32 + lg * 8);
      acc[nt] = __builtin_amdgcn_mfma_f32_16x16x32_bf16(af, bf, acc[nt], 0, 0, 0);
    }
  }
#pragma unroll
  for (int nt = 0; nt < 12; ++nt) {
#pragma unroll
    for (int j = 0; j < 4; ++j) {
      int lr = m * 16 + lg * 4 + j;
      int col = nh * 192 + nt * 16 + l15;
      th_l[lr][col] = f2bu(tanh_fast(acc[nt][j]));
    }
  }
  __syncthreads();

  // 960 dots: task = (local_row, r); abuf[b][r][t] = th_l[lr][:350] . W2[r]
  for (int task = threadIdx.x; task < 32 * R_; task += 256) {
    int lr = task / R_, r = task - lr * R_;
    const float* wp = W2 + r * AD_;
    const unsigned short* tp = &th_l[lr][0];
    float s = 0.f;
#pragma unroll 2
    for (int a = 0; a < AD_; ++a) s = fmaf(b2f(tp[a]), wp[a], s);
    int grow = rb * 32 + lr;
    int b = grow >> 9, t = grow & 511;
    abuf[((size_t)b * R_ + r) * T_ + t] = s;
  }
}

// ---------------------------------------------------------------------------
// K5 v2 (fused k5+k7): block = b.  Load A (30x512) to LDS, masked softmax
//   per row (8 waves x up-to-4 rows), write back; then ||A A^T - I||_F^2
//   partial in-block -> penp[b].
// ---------------------------------------------------------------------------
__global__ __launch_bounds__(512, 1) void k5_sm(float* __restrict__ abuf,
                                                const int* __restrict__ lens,
                                                float* __restrict__ penp) {
  const int b = blockIdx.x;
  const int tid = threadIdx.x;
  __shared__ float As[R_ * 515];
  __shared__ float red[512];

  for (int i = tid; i < R_ * T_; i += 512) {
    int r = i >> 9, t = i & 511;
    As[r * 515 + t] = abuf[(size_t)b * R_ * T_ + i];
  }
  __syncthreads();

  const int len = lens[b];
  const int wv = tid >> 6, lane = tid & 63;
#pragma unroll 1
  for (int k = 0; k < 4; ++k) {
    int r = wv * 4 + k;
    if (r >= R_) break;
    float* row = As + r * 515;
    float v[8];
    float mx = -1e30f;
#pragma unroll
    for (int i = 0; i < 8; ++i) {
      int t = lane + i * 64;
      float x = (t < len) ? row[t] : -1e30f;
      v[i] = x;
      mx = fmaxf(mx, x);
    }
#pragma unroll
    for (int o = 32; o > 0; o >>= 1) mx = fmaxf(mx, __shfl_xor(mx, o));
    float sum = 0.f;
#pragma unroll
    for (int i = 0; i < 8; ++i) {
      float e = (v[i] > -1e29f) ? __expf(v[i] - mx) : 0.f;
      v[i] = e;
      sum += e;
    }
#pragma unroll
    for (int o = 32; o > 0; o >>= 1) sum += __shfl_xor(sum, o);
    float inv = 1.f / sum;
#pragma unroll
    for (int i = 0; i < 8; ++i) {
      int t = lane + i * 64;
      float e = v[i] * inv;
      row[t] = e;
      abuf[(size_t)b * R_ * T_ + r * T_ + t] = e;
    }
  }
  __syncthreads();

  // penalty: 900 (r,s) pairs, 512-dot each over LDS rows
  float psum = 0.f;
  for (int task = tid; task < R_ * R_; task += 512) {
    int r = task / R_, s2 = task - (task / R_) * R_;
    const float* pr = As + r * 515;
    const float* ps = As + s2 * 515;
    float d = 0.f;
    for (int t = 0; t < T_; ++t) d = fmaf(pr[t], ps[t], d);
    d -= (r == s2) ? 1.f : 0.f;
    psum += d * d;
  }
  red[tid] = psum;
  __syncthreads();
  for (int o = 256; o > 0; o >>= 1) {
    if (tid < o) red[tid] += red[tid + o];
    __syncthreads();
  }
  if (tid == 0) penp[b] = red[0];
}

// ---------------------------------------------------------------------------
// K6: M[b][r][h] = sum_t A[b][r][t] * out[b][t][h].  Writes mbuf as bf16.
// ---------------------------------------------------------------------------
__global__ __launch_bounds__(256) void k6_m(const float* __restrict__ abuf,
                                            const unsigned short* __restrict__ outb,
                                            unsigned short* __restrict__ mbuf) {
  int b = blockIdx.x >> 4, hb = blockIdx.x & 15;
  __shared__ float As[R_ * T_];
  for (int i = threadIdx.x; i < R_ * T_; i += 256) As[i] = abuf[(size_t)b * R_ * T_ + i];
  __syncthreads();
  int h = threadIdx.x & 127, rh = threadIdx.x >> 7;
  float acc[15];
#pragma unroll
  for (int rr = 0; rr < 15; ++rr) acc[rr] = 0.f;
  const unsigned short* op = outb + (size_t)b * T_ * 2048 + hb * 128 + h;
  for (int t = 0; t < T_; ++t) {
    float vv = b2f(op[(size_t)t * 2048]);
#pragma unroll
    for (int rr = 0; rr < 15; ++rr) acc[rr] = fmaf(As[(rh * 15 + rr) * T_ + t], vv, acc[rr]);
  }
#pragma unroll
  for (int rr = 0; rr < 15; ++rr)
    mbuf[(size_t)b * FEAT_ + (size_t)(rh * 15 + rr) * 2048 + hb * 128 + h] = f2bu(acc[rr]);
}

// ---------------------------------------------------------------------------
// K8 v3: hidsum[b][m] += W_mlp(fp32, cast in-reg)[m-tile] . mbuf[b]  (MFMA)
// ---------------------------------------------------------------------------
__global__ __launch_bounds__(256, 1) void k8_mlp(const float* __restrict__ W_mlp,
                                                 const unsigned short* __restrict__ mbuf,
                                                 float* __restrict__ hid) {
  const int mblk = blockIdx.x >> 4, kblk = blockIdx.x & 15;
  const int wid = threadIdx.x >> 6, lane = threadIdx.x & 63;
  const int l15 = lane & 15, lg = lane >> 4;
  const int kq = kblk * 3840 + wid * 960;

  f32x4 acc[2][2];
#pragma unroll
  for (int i = 0; i < 2; ++i)
#pragma unroll
    for (int j = 0; j < 2; ++j) acc[i][j] = (f32x4){0.f, 0.f, 0.f, 0.f};

  const float* ap0f = W_mlp + (size_t)(mblk * 32 + l15) * FEAT_ + kq + lg * 8;
  const float* ap1f = ap0f + (size_t)16 * FEAT_;
  const unsigned short* bp0 = mbuf + (size_t)l15 * FEAT_ + kq + lg * 8;
  const unsigned short* bp1 = bp0 + (size_t)16 * FEAT_;
  for (int kt = 0; kt < 30; ++kt) {
    float4 f0 = *(const float4*)(ap0f + kt * 32);
    float4 f1 = *(const float4*)(ap0f + kt * 32 + 4);
    float4 g0 = *(const float4*)(ap1f + kt * 32);
    float4 g1 = *(const float4*)(ap1f + kt * 32 + 4);
    short8 a0, a1;
    a0[0] = (short)f2bu(f0.x); a0[1] = (short)f2bu(f0.y);
    a0[2] = (short)f2bu(f0.z); a0[3] = (short)f2bu(f0.w);
    a0[4] = (short)f2bu(f1.x); a0[5] = (short)f2bu(f1.y);
    a0[6] = (short)f2bu(f1.z); a0[7] = (short)f2bu(f1.w);
    a1[0] = (short)f2bu(g0.x); a1[1] = (short)f2bu(g0.y);
    a1[2] = (short)f2bu(g0.z); a1[3] = (short)f2bu(g0.w);
    a1[4] = (short)f2bu(g1.x); a1[5] = (short)f2bu(g1.y);
    a1[6] = (short)f2bu(g1.z); a1[7] = (short)f2bu(g1.w);
    short8 b0 = *(const short8*)(bp0 + kt * 32);
    short8 b1 = *(const short8*)(bp1 + kt * 32);
    acc[0][0] = __builtin_amdgcn_mfma_f32_16x16x32_bf16(a0, b0, acc[0][0], 0, 0, 0);
    acc[0][1] = __builtin_amdgcn_mfma_f32_16x16x32_bf16(a0, b1, acc[0][1], 0, 0, 0);
    acc[1][0] = __builtin_amdgcn_mfma_f32_16x16x32_bf16(a1, b0, acc[1][0], 0, 0, 0);
    acc[1][1] = __builtin_amdgcn_mfma_f32_16x16x32_bf16(a1, b1, acc[1][1], 0, 0, 0);
  }

  __shared__ float red[4][32][33];
#pragma unroll
  for (int mi = 0; mi < 2; ++mi)
#pragma unroll
    for (int ni = 0; ni < 2; ++ni)
#pragma unroll
      for (int j = 0; j < 4; ++j)
        red[wid][mi * 16 + lg * 4 + j][ni * 16 + l15] = acc[mi][ni][j];
  __syncthreads();

  int m = threadIdx.x >> 3, b4 = (threadIdx.x & 7) * 4;
#pragma unroll
  for (int k = 0; k < 4; ++k) {
    int bb = b4 + k;
    float s = red[0][m][bb] + red[1][m][bb] + red[2][m][bb] + red[3][m][bb];
    atomicAdd(&hid[(size_t)bb * MH_ + mblk * 32 + m], s);
  }
}

// ---------------------------------------------------------------------------
// K9: decoded = softmax( relu(hid+b_mlp) @ W_dec^T + b_dec ); penal = mean.
// ---------------------------------------------------------------------------
__global__ void k9_out(const float* __restrict__ hid, const float* __restrict__ b_mlp,
                       const float* __restrict__ W_dec, const float* __restrict__ b_dec,
                       const float* __restrict__ penp, float* __restrict__ out) {
  int tid = threadIdx.x;
  if (tid < 64) {
    int b = tid >> 1, c = tid & 1;
    const float* hp = hid + (size_t)b * MH_;
    const float* wp = W_dec + (size_t)c * MH_;
    float acc = b_dec[c];
    for (int k = 0; k < MH_; ++k) {
      float hk = fmaxf(hp[k] + b_mlp[k], 0.f);
      acc = fmaf(hk, wp[k], acc);
    }
    float other = __shfl_xor(acc, 1);
    float mx = fmaxf(acc, other);
    float e = __expf(acc - mx), eo = __expf(other - mx);
    out[b * 2 + c] = e / (e + eo);
  } else if (tid == 64) {
    float s = 0.f;
    for (int b = 0; b < B_; ++b) s += penp[b];
    out[64] = s * (1.f / 32.f);
  }
}

// ---------------------------------------------------------------------------
extern "C" void kernel_launch(void* const* d_in, const int* in_sizes, int n_in,
                              void* d_out, int out_size, void* d_ws, size_t ws_size,
                              hipStream_t stream) {
  const int* inp = (const int*)d_in[0];
  const int* lens = (const int*)d_in[1];
  const float* W_emb = (const float*)d_in[2];
  const float* W_ih = (const float*)d_in[3];
  const float* W_hh = (const float*)d_in[4];
  const float* b_ih = (const float*)d_in[5];
  const float* b_hh = (const float*)d_in[6];
  const float* W1 = (const float*)d_in[7];
  const float* W2 = (const float*)d_in[8];
  const float* W_mlp = (const float*)d_in[9];
  const float* b_mlp = (const float*)d_in[10];
  const float* W_dec = (const float*)d_in[11];
  const float* b_dec = (const float*)d_in[12];
  float* out = (float*)d_out;

  char* ws = (char*)d_ws;
  size_t off = 0;
  auto take = [&](size_t bytes) -> char* {
    char* p = ws + off;
    off = (off + bytes + 255) & ~(size_t)255;
    return p;
  };
  unsigned short* outb = (unsigned short*)take((size_t)B_ * T_ * 2048 * 2);     // 67.1 MB
  unsigned short* hpub = (unsigned short*)take((size_t)2 * T_ * 2 * 16384 * 2); // 67.1 MB
  unsigned short* xb = (unsigned short*)take((size_t)16384 * KE_ * 2);          // 12.6 MB
  unsigned short* wihb = (unsigned short*)take((size_t)8192 * KE_ * 2);         // 6.3 MB
  unsigned short* w1b = (unsigned short*)take((size_t)AC_ * 2048 * 2);          // 1.6 MB
  float* abuf = (float*)take((size_t)B_ * R_ * T_ * 4);                         // 2.0 MB
  unsigned short* mbuf = (unsigned short*)take((size_t)B_ * FEAT_ * 2);         // 3.9 MB
  float* penp = (float*)take(B_ * 4);
  float* hid = (float*)take((size_t)B_ * MH_ * 4);

  if (off > ws_size) {  // unambiguous failure signal: NaN output
    hipMemsetAsync(d_out, 0xFF, (size_t)out_size * 4, stream);
    return;
  }

  // sentinel-init hpub: 0xFFFF bf16 has bit14 set => "unwritten" marker
  hipMemsetAsync(hpub, 0xFF, (size_t)2 * T_ * 2 * 16384 * 2, stream);
  hipMemsetAsync(hid, 0, (size_t)B_ * MH_ * 4, stream);

  k0_prep<<<2048, 256, 0, stream>>>(inp, W_emb, W_ih, W1, xb, wihb, w1b);
  k2_rnn<<<256, 256, 0, stream>>>(W_hh, wihb, xb, b_ih, b_hh, outb, hpub);
  k3_s1<<<512, 256, 0, stream>>>(outb, w1b, W2, abuf);
  k5_sm<<<32, 512, 0, stream>>>(abuf, lens, penp);
  k6_m<<<512, 256, 0, stream>>>(abuf, outb, mbuf);
  k8_mlp<<<256, 256, 0, stream>>>(W_mlp, mbuf, hid);
  k9_out<<<1, 128, 0, stream>>>(hid, b_mlp, W_dec, b_dec, penp, out);
}